// Round 2
// baseline (338.234 us; speedup 1.0000x reference)
//
#include <hip/hip_runtime.h>
#include <hip/hip_bf16.h>

typedef __attribute__((ext_vector_type(8))) short short8;
typedef __attribute__((ext_vector_type(4))) float floatx4;
typedef __attribute__((ext_vector_type(4))) unsigned short ushort4v;
typedef __attribute__((ext_vector_type(8))) unsigned short ushort8v;
typedef __attribute__((ext_vector_type(2))) unsigned int uint2v;
typedef __attribute__((ext_vector_type(4))) unsigned int uint4v;

#define NN 10000
#define E0 160000
#define ETOT (E0 + NN)
#define IN_DIM 512
#define HID1 1024   /* HEADS*HID = 8*128 */
#define EMB 256
#define MPAD 10112  /* 79 * 128 */
#define LDSS 40     /* LDS row stride (32 + 8 pad) */

__device__ __forceinline__ float bf2f(unsigned short u) {
    unsigned v = ((unsigned)u) << 16;
    float f;
    __builtin_memcpy(&f, &v, 4);
    return f;
}
__device__ __forceinline__ float bflo(unsigned v) {
    unsigned x = v << 16;
    float f; __builtin_memcpy(&f, &x, 4);
    return f;
}
__device__ __forceinline__ float bfhi(unsigned v) {
    unsigned x = v & 0xffff0000u;
    float f; __builtin_memcpy(&f, &x, 4);
    return f;
}
__device__ __forceinline__ unsigned short f2bf(float f) {
    unsigned u;
    __builtin_memcpy(&u, &f, 4);
    unsigned lsb = (u >> 16) & 1;
    u += 0x7fff + lsb;           // round-to-nearest-even
    return (unsigned short)(u >> 16);
}
__device__ __forceinline__ unsigned packbf(float lo, float hi) {
    return (unsigned)f2bf(lo) | ((unsigned)f2bf(hi) << 16);
}
__device__ __forceinline__ float loadf(const void* p, size_t i, int isf32) {
    if (isf32) return ((const float*)p)[i];
    return bf2f(((const unsigned short*)p)[i]);
}
__device__ __forceinline__ float lrelu(float e) { return e > 0.f ? e : 0.2f * e; }

// ---------------- zero fill ----------------
__global__ void zero_kernel(int* p, int n) {
    int i = blockIdx.x * 256 + threadIdx.x;
    if (i < n) p[i] = 0;
}

// ---------------- float dtype probe ----------------
__global__ __launch_bounds__(1024) void fdetect_kernel(const unsigned* xw, int* isf32) {
    __shared__ int cnt[1024];
    int t = threadIdx.x;
    int c = 0;
    #pragma unroll
    for (int j = 0; j < 4; ++j) {
        unsigned w = xw[t * 4 + j];
        int ex = (w >> 7) & 0xFF;
        if (ex >= 110 && ex <= 135) c++;
    }
    cnt[t] = c;
    __syncthreads();
    for (int off = 512; off > 0; off >>= 1) {
        if (t < off) cnt[t] += cnt[t + off];
        __syncthreads();
    }
    if (t == 0) *isf32 = (cnt[0] < 2048) ? 1 : 0;
}

// ---------------- edge dtype probe ----------------
__global__ void detect_kernel(const int* ei32, int* flag) {
    int i = blockIdx.x * 256 + threadIdx.x;
    int v = 0;
    int idx = 2 * i + 1;
    if (idx < 2 * E0) v = ei32[idx];
    unsigned long long any = __ballot(v != 0);
    if (any && (threadIdx.x & 63) == 0) atomicOr(flag, 1);
}

__device__ __forceinline__ int load_edge(const void* ei, long long idx, int m32) {
    if (m32) return ((const int*)ei)[idx];
    return (int)(((const long long*)ei)[idx]);
}

// ---------------- CSR build ----------------
__global__ void count_kernel(const void* ei, const int* flag, int* counts) {
    int e = blockIdx.x * 256 + threadIdx.x;
    if (e < E0) {
        int m32 = (*flag != 0);
        int d = load_edge(ei, (long long)E0 + e, m32);
        if (d >= 0 && d < NN) atomicAdd(&counts[d], 1);
    }
}

__global__ __launch_bounds__(1024) void scan_kernel(const int* counts, int* offsets, int* cursor) {
    __shared__ int part[1024];
    int t = threadIdx.x;
    int base = t * 10;
    int local[10];
    int s = 0;
    for (int j = 0; j < 10; ++j) {
        int idx = base + j;
        int v = (idx < NN) ? (counts[idx] + 1) : 0;  // +1 self loop
        local[j] = v; s += v;
    }
    part[t] = s;
    __syncthreads();
    for (int off = 1; off < 1024; off <<= 1) {
        int v = (t >= off) ? part[t - off] : 0;
        __syncthreads();
        part[t] += v;
        __syncthreads();
    }
    int run = (t == 0) ? 0 : part[t - 1];
    for (int j = 0; j < 10; ++j) {
        int idx = base + j;
        if (idx < NN) { offsets[idx] = run; cursor[idx] = run; run += local[j]; }
    }
    if (t == 1023) offsets[NN] = part[1023];
}

__global__ void scatter_kernel(const void* ei, const int* flag, int* cursor, int* csr_src) {
    int e = blockIdx.x * 256 + threadIdx.x;
    if (e >= ETOT) return;
    int m32 = (*flag != 0);
    int s, d;
    if (e < E0) { s = load_edge(ei, e, m32); d = load_edge(ei, (long long)E0 + e, m32); }
    else { s = d = e - E0; }
    if (s < 0) s = 0; if (s >= NN) s = NN - 1;
    if (d < 0) d = 0; if (d >= NN) d = NN - 1;
    int pos = atomicAdd(&cursor[d], 1);
    if (pos >= 0 && pos < ETOT) csr_src[pos] = s;
}

// ---------------- fp32->bf16 conversions ----------------
__global__ void conv_kernel(const void* in, unsigned short* out, int n, const int* isf32) {
    int i = blockIdx.x * 256 + threadIdx.x;
    if (i < n) out[i] = f2bf(loadf(in, i, *isf32));
}

__global__ void convT_kernel(const void* in, unsigned short* out, int R, int C, const int* isf32) {
    int i = blockIdx.x * 256 + threadIdx.x;
    if (i < R * C) {
        int r = i / C, c = i % C;
        out[(size_t)c * R + r] = f2bf(loadf(in, i, *isf32));
    }
}

// ---------------- LDS-tiled bf16 MFMA GEMM: C[Mpad,N] = A[Mpad,K] * Bt[N,K]^T ----------------
template<bool OUTBF16>
__global__ __launch_bounds__(256) void gemm_tile(
    const unsigned short* __restrict__ A,
    const unsigned short* __restrict__ Bt,
    void* __restrict__ Cv,
    int N, int K)
{
    __shared__ unsigned short As[128 * LDSS];
    __shared__ unsigned short Bs[128 * LDSS];
    int t = threadIdx.x;
    int wave = t >> 6;
    int lane = t & 63;
    int quad = lane >> 4;
    int l16  = lane & 15;
    int mq = wave & 1, nq = wave >> 1;
    size_t mblk = (size_t)blockIdx.x * 128;
    size_t nblk = (size_t)blockIdx.y * 128;

    int srow = t >> 2;
    int skof = (t & 3) * 8;

    floatx4 acc[4][4];
    #pragma unroll
    for (int i = 0; i < 4; ++i)
        #pragma unroll
        for (int j = 0; j < 4; ++j)
            acc[i][j] = (floatx4){0.f, 0.f, 0.f, 0.f};

    const unsigned short* Ab = A + mblk * K + skof;
    const unsigned short* Bb = Bt + nblk * K + skof;

    for (int kk = 0; kk < K; kk += 32) {
        short8 a0 = *(const short8*)(const void*)(Ab + (size_t)srow * K + kk);
        short8 a1 = *(const short8*)(const void*)(Ab + (size_t)(srow + 64) * K + kk);
        short8 b0 = *(const short8*)(const void*)(Bb + (size_t)srow * K + kk);
        short8 b1 = *(const short8*)(const void*)(Bb + (size_t)(srow + 64) * K + kk);
        __syncthreads();
        *(short8*)(void*)(As + srow * LDSS + skof)        = a0;
        *(short8*)(void*)(As + (srow + 64) * LDSS + skof) = a1;
        *(short8*)(void*)(Bs + srow * LDSS + skof)        = b0;
        *(short8*)(void*)(Bs + (srow + 64) * LDSS + skof) = b1;
        __syncthreads();

        short8 af[4], bf[4];
        #pragma unroll
        for (int i = 0; i < 4; ++i) {
            af[i] = *(const short8*)(const void*)(As + (mq * 64 + i * 16 + l16) * LDSS + quad * 8);
            bf[i] = *(const short8*)(const void*)(Bs + (nq * 64 + i * 16 + l16) * LDSS + quad * 8);
        }
        #pragma unroll
        for (int i = 0; i < 4; ++i)
            #pragma unroll
            for (int j = 0; j < 4; ++j)
                acc[i][j] = __builtin_amdgcn_mfma_f32_16x16x32_bf16(af[i], bf[j], acc[i][j], 0, 0, 0);
    }

    size_t crow0 = mblk + mq * 64 + quad * 4;
    size_t ccol0 = nblk + nq * 64 + l16;
    #pragma unroll
    for (int i = 0; i < 4; ++i) {
        #pragma unroll
        for (int r = 0; r < 4; ++r) {
            size_t row = crow0 + i * 16 + r;
            size_t b = row * N + ccol0;
            #pragma unroll
            for (int j = 0; j < 4; ++j) {
                if (OUTBF16) ((unsigned short*)Cv)[b + j * 16] = f2bf(acc[i][j][r]);
                else         ((float*)Cv)[b + j * 16] = acc[i][j][r];
            }
        }
    }
}

// ---------------- alpha for layer 1 (bf16 h1): as1/ad1 [N,8] ----------------
// wave-per-node: lane covers 16 contiguous cols; head = lane>>3; shfl reduce over 8 lanes.
__global__ __launch_bounds__(256) void alpha1_kernel(
    const unsigned short* __restrict__ h1,
    const void* __restrict__ a_src, const void* __restrict__ a_dst,
    const int* __restrict__ isf32,
    float* __restrict__ as1, float* __restrict__ ad1)
{
    int n = blockIdx.x * 4 + (threadIdx.x >> 6);
    if (n >= NN) return;
    int lane = threadIdx.x & 63;
    int f = *isf32;
    int h = lane >> 3;           // 8 lanes per head (8 heads)
    const unsigned* h1w = (const unsigned*)h1;
    uint4v v0 = *(const uint4v*)(const void*)(h1w + (size_t)n * 512 + lane * 8);
    uint4v v1 = *(const uint4v*)(const void*)(h1w + (size_t)n * 512 + lane * 8 + 4);
    int c0 = lane * 16;
    float ps = 0.f, pd = 0.f;
    #pragma unroll
    for (int q = 0; q < 4; ++q) {
        float e0 = bflo(v0[q]), e1 = bfhi(v0[q]);
        ps += e0 * loadf(a_src, c0 + 2 * q, f)     + e1 * loadf(a_src, c0 + 2 * q + 1, f);
        pd += e0 * loadf(a_dst, c0 + 2 * q, f)     + e1 * loadf(a_dst, c0 + 2 * q + 1, f);
        float e2 = bflo(v1[q]), e3 = bfhi(v1[q]);
        ps += e2 * loadf(a_src, c0 + 8 + 2 * q, f) + e3 * loadf(a_src, c0 + 8 + 2 * q + 1, f);
        pd += e2 * loadf(a_dst, c0 + 8 + 2 * q, f) + e3 * loadf(a_dst, c0 + 8 + 2 * q + 1, f);
    }
    #pragma unroll
    for (int off = 1; off < 8; off <<= 1) {
        ps += __shfl_xor(ps, off, 64);
        pd += __shfl_xor(pd, off, 64);
    }
    if ((lane & 7) == 0) {
        as1[n * 8 + h] = ps;
        ad1[n * 8 + h] = pd;
    }
}

// ---------------- layer-1 single-pass softmax-aggregate + ELU -> hmid bf16 ----------------
// ONE WAVE PER NODE: 64 lanes x 16 cols (8 from each half-row, 2 heads per lane).
// Every lane sees every edge -> denominators accumulate redundantly per lane, no
// reduction / LDS / syncthreads needed. 4-deep edge pipeline for MLP.
__global__ __launch_bounds__(256, 5) void agg1_kernel(
    const unsigned short* __restrict__ h1, const int* __restrict__ offsets,
    const int* __restrict__ csr_src, const float* __restrict__ as1,
    const float* __restrict__ ad1, const void* __restrict__ b1,
    const int* __restrict__ isf32,
    unsigned short* __restrict__ hmid)
{
    int n = blockIdx.x * 4 + (threadIdx.x >> 6);
    if (n >= NN) return;
    int lane = threadIdx.x & 63;
    int f = *isf32;
    int beg = offsets[n], end = offsets[n + 1];
    if (beg < 0) beg = 0; if (end > ETOT) end = ETOT;
    int hA = lane >> 4;          // head of cols [lane*8, lane*8+8)
    int hB = hA + 4;             // head of cols [512+lane*8, ...)
    float adA = ad1[n * 8 + hA];
    float adB = ad1[n * 8 + hB];
    const unsigned* rbase = (const unsigned*)h1 + lane * 4;   // + s*512 (+256 for half B)

    float denA = 0.f, denB = 0.f;
    float accA[8], accB[8];
    #pragma unroll
    for (int j = 0; j < 8; ++j) { accA[j] = 0.f; accB[j] = 0.f; }

    int i = beg;
    // 4 edges in flight
    for (; i + 3 < end; i += 4) {
        int s0 = csr_src[i];     s0 &= 0x7fffffff; if (s0 >= NN) s0 = 0;
        int s1 = csr_src[i + 1]; s1 &= 0x7fffffff; if (s1 >= NN) s1 = 0;
        int s2 = csr_src[i + 2]; s2 &= 0x7fffffff; if (s2 >= NN) s2 = 0;
        int s3 = csr_src[i + 3]; s3 &= 0x7fffffff; if (s3 >= NN) s3 = 0;
        uint4v a0 = *(const uint4v*)(const void*)(rbase + (size_t)s0 * 512);
        uint4v b0 = *(const uint4v*)(const void*)(rbase + (size_t)s0 * 512 + 256);
        uint4v a1 = *(const uint4v*)(const void*)(rbase + (size_t)s1 * 512);
        uint4v b1v = *(const uint4v*)(const void*)(rbase + (size_t)s1 * 512 + 256);
        uint4v a2 = *(const uint4v*)(const void*)(rbase + (size_t)s2 * 512);
        uint4v b2v = *(const uint4v*)(const void*)(rbase + (size_t)s2 * 512 + 256);
        uint4v a3 = *(const uint4v*)(const void*)(rbase + (size_t)s3 * 512);
        uint4v b3v = *(const uint4v*)(const void*)(rbase + (size_t)s3 * 512 + 256);
        float wA0 = __expf(lrelu(as1[s0 * 8 + hA] + adA));
        float wA1 = __expf(lrelu(as1[s1 * 8 + hA] + adA));
        float wA2 = __expf(lrelu(as1[s2 * 8 + hA] + adA));
        float wA3 = __expf(lrelu(as1[s3 * 8 + hA] + adA));
        float wB0 = __expf(lrelu(as1[s0 * 8 + hB] + adB));
        float wB1 = __expf(lrelu(as1[s1 * 8 + hB] + adB));
        float wB2 = __expf(lrelu(as1[s2 * 8 + hB] + adB));
        float wB3 = __expf(lrelu(as1[s3 * 8 + hB] + adB));
        denA += (wA0 + wA1) + (wA2 + wA3);
        denB += (wB0 + wB1) + (wB2 + wB3);
        #pragma unroll
        for (int q = 0; q < 4; ++q) {
            accA[2 * q]     += (bflo(a0[q]) * wA0 + bflo(a1[q]) * wA1) + (bflo(a2[q]) * wA2 + bflo(a3[q]) * wA3);
            accA[2 * q + 1] += (bfhi(a0[q]) * wA0 + bfhi(a1[q]) * wA1) + (bfhi(a2[q]) * wA2 + bfhi(a3[q]) * wA3);
            accB[2 * q]     += (bflo(b0[q]) * wB0 + bflo(b1v[q]) * wB1) + (bflo(b2v[q]) * wB2 + bflo(b3v[q]) * wB3);
            accB[2 * q + 1] += (bfhi(b0[q]) * wB0 + bfhi(b1v[q]) * wB1) + (bfhi(b2v[q]) * wB2 + bfhi(b3v[q]) * wB3);
        }
    }
    // 2 edges in flight
    for (; i + 1 < end; i += 2) {
        int s0 = csr_src[i];     s0 &= 0x7fffffff; if (s0 >= NN) s0 = 0;
        int s1 = csr_src[i + 1]; s1 &= 0x7fffffff; if (s1 >= NN) s1 = 0;
        uint4v a0 = *(const uint4v*)(const void*)(rbase + (size_t)s0 * 512);
        uint4v b0 = *(const uint4v*)(const void*)(rbase + (size_t)s0 * 512 + 256);
        uint4v a1 = *(const uint4v*)(const void*)(rbase + (size_t)s1 * 512);
        uint4v b1v = *(const uint4v*)(const void*)(rbase + (size_t)s1 * 512 + 256);
        float wA0 = __expf(lrelu(as1[s0 * 8 + hA] + adA));
        float wA1 = __expf(lrelu(as1[s1 * 8 + hA] + adA));
        float wB0 = __expf(lrelu(as1[s0 * 8 + hB] + adB));
        float wB1 = __expf(lrelu(as1[s1 * 8 + hB] + adB));
        denA += wA0 + wA1;
        denB += wB0 + wB1;
        #pragma unroll
        for (int q = 0; q < 4; ++q) {
            accA[2 * q]     += bflo(a0[q]) * wA0 + bflo(a1[q]) * wA1;
            accA[2 * q + 1] += bfhi(a0[q]) * wA0 + bfhi(a1[q]) * wA1;
            accB[2 * q]     += bflo(b0[q]) * wB0 + bflo(b1v[q]) * wB1;
            accB[2 * q + 1] += bfhi(b0[q]) * wB0 + bfhi(b1v[q]) * wB1;
        }
    }
    // tail
    if (i < end) {
        int s0 = csr_src[i]; s0 &= 0x7fffffff; if (s0 >= NN) s0 = 0;
        uint4v a0 = *(const uint4v*)(const void*)(rbase + (size_t)s0 * 512);
        uint4v b0 = *(const uint4v*)(const void*)(rbase + (size_t)s0 * 512 + 256);
        float wA0 = __expf(lrelu(as1[s0 * 8 + hA] + adA));
        float wB0 = __expf(lrelu(as1[s0 * 8 + hB] + adB));
        denA += wA0;
        denB += wB0;
        #pragma unroll
        for (int q = 0; q < 4; ++q) {
            accA[2 * q]     += bflo(a0[q]) * wA0;
            accA[2 * q + 1] += bfhi(a0[q]) * wA0;
            accB[2 * q]     += bflo(b0[q]) * wB0;
            accB[2 * q + 1] += bfhi(b0[q]) * wB0;
        }
    }

    float rdA = 1.0f / fmaxf(denA, 1e-30f);
    float rdB = 1.0f / fmaxf(denB, 1e-30f);
    uint4v oA, oB;
    #pragma unroll
    for (int q = 0; q < 4; ++q) {
        int c = lane * 8 + 2 * q;
        float v0 = accA[2 * q]     * rdA + loadf(b1, c, f);
        float v1 = accA[2 * q + 1] * rdA + loadf(b1, c + 1, f);
        v0 = v0 > 0.f ? v0 : (__expf(v0) - 1.0f);
        v1 = v1 > 0.f ? v1 : (__expf(v1) - 1.0f);
        oA[q] = packbf(v0, v1);
        float u0 = accB[2 * q]     * rdB + loadf(b1, 512 + c, f);
        float u1 = accB[2 * q + 1] * rdB + loadf(b1, 512 + c + 1, f);
        u0 = u0 > 0.f ? u0 : (__expf(u0) - 1.0f);
        u1 = u1 > 0.f ? u1 : (__expf(u1) - 1.0f);
        oB[q] = packbf(u0, u1);
    }
    unsigned* hw = (unsigned*)hmid;
    *(uint4v*)(void*)(hw + (size_t)n * 512 + lane * 4)       = oA;
    *(uint4v*)(void*)(hw + (size_t)n * 512 + 256 + lane * 4) = oB;
}

// ---------------- alpha for layer 2 (bf16 h2): as2/ad2 [N] ----------------
// wave-per-node, full 64-lane shfl reduce.
__global__ __launch_bounds__(256) void alpha2_kernel(
    const unsigned short* __restrict__ h2,
    const void* __restrict__ a_src2, const void* __restrict__ a_dst2,
    const int* __restrict__ isf32,
    float* __restrict__ as2, float* __restrict__ ad2)
{
    int n = blockIdx.x * 4 + (threadIdx.x >> 6);
    if (n >= NN) return;
    int lane = threadIdx.x & 63;
    int f = *isf32;
    const unsigned* h2w = (const unsigned*)h2;
    uint2v v = *(const uint2v*)(const void*)(h2w + (size_t)n * 128 + lane * 2);
    int c0 = lane * 4;
    float e0 = bflo(v[0]), e1 = bfhi(v[0]), e2 = bflo(v[1]), e3 = bfhi(v[1]);
    float ps = e0 * loadf(a_src2, c0, f) + e1 * loadf(a_src2, c0 + 1, f)
             + e2 * loadf(a_src2, c0 + 2, f) + e3 * loadf(a_src2, c0 + 3, f);
    float pd = e0 * loadf(a_dst2, c0, f) + e1 * loadf(a_dst2, c0 + 1, f)
             + e2 * loadf(a_dst2, c0 + 2, f) + e3 * loadf(a_dst2, c0 + 3, f);
    #pragma unroll
    for (int off = 1; off < 64; off <<= 1) {
        ps += __shfl_xor(ps, off, 64);
        pd += __shfl_xor(pd, off, 64);
    }
    if (lane == 0) { as2[n] = ps; ad2[n] = pd; }
}

// ---------------- layer-2 single-pass softmax-aggregate -> out fp32 ----------------
// ONE WAVE PER NODE: 64 lanes x 4 cols; weight math wave-uniform; no LDS/sync.
__global__ __launch_bounds__(256) void agg2_kernel(
    const unsigned short* __restrict__ h2, const int* __restrict__ offsets,
    const int* __restrict__ csr_src, const float* __restrict__ as2,
    const float* __restrict__ ad2, const void* __restrict__ b2,
    const int* __restrict__ isf32,
    float* __restrict__ out)
{
    int n = blockIdx.x * 4 + (threadIdx.x >> 6);
    if (n >= NN) return;
    int lane = threadIdx.x & 63;
    int f = *isf32;
    int beg = offsets[n], end = offsets[n + 1];
    if (beg < 0) beg = 0; if (end > ETOT) end = ETOT;
    float adn = ad2[n];
    const unsigned* rbase = (const unsigned*)h2 + lane * 2;  // + s*128

    float den = 0.f;
    float acc[4];
    #pragma unroll
    for (int j = 0; j < 4; ++j) acc[j] = 0.f;

    int i = beg;
    for (; i + 3 < end; i += 4) {
        int s0 = csr_src[i];     s0 &= 0x7fffffff; if (s0 >= NN) s0 = 0;
        int s1 = csr_src[i + 1]; s1 &= 0x7fffffff; if (s1 >= NN) s1 = 0;
        int s2 = csr_src[i + 2]; s2 &= 0x7fffffff; if (s2 >= NN) s2 = 0;
        int s3 = csr_src[i + 3]; s3 &= 0x7fffffff; if (s3 >= NN) s3 = 0;
        uint2v v0 = *(const uint2v*)(const void*)(rbase + (size_t)s0 * 128);
        uint2v v1 = *(const uint2v*)(const void*)(rbase + (size_t)s1 * 128);
        uint2v v2 = *(const uint2v*)(const void*)(rbase + (size_t)s2 * 128);
        uint2v v3 = *(const uint2v*)(const void*)(rbase + (size_t)s3 * 128);
        float w0 = __expf(lrelu(as2[s0] + adn));
        float w1 = __expf(lrelu(as2[s1] + adn));
        float w2 = __expf(lrelu(as2[s2] + adn));
        float w3 = __expf(lrelu(as2[s3] + adn));
        den += (w0 + w1) + (w2 + w3);
        acc[0] += (bflo(v0[0]) * w0 + bflo(v1[0]) * w1) + (bflo(v2[0]) * w2 + bflo(v3[0]) * w3);
        acc[1] += (bfhi(v0[0]) * w0 + bfhi(v1[0]) * w1) + (bfhi(v2[0]) * w2 + bfhi(v3[0]) * w3);
        acc[2] += (bflo(v0[1]) * w0 + bflo(v1[1]) * w1) + (bflo(v2[1]) * w2 + bflo(v3[1]) * w3);
        acc[3] += (bfhi(v0[1]) * w0 + bfhi(v1[1]) * w1) + (bfhi(v2[1]) * w2 + bfhi(v3[1]) * w3);
    }
    for (; i + 1 < end; i += 2) {
        int s0 = csr_src[i];     s0 &= 0x7fffffff; if (s0 >= NN) s0 = 0;
        int s1 = csr_src[i + 1]; s1 &= 0x7fffffff; if (s1 >= NN) s1 = 0;
        uint2v v0 = *(const uint2v*)(const void*)(rbase + (size_t)s0 * 128);
        uint2v v1 = *(const uint2v*)(const void*)(rbase + (size_t)s1 * 128);
        float w0 = __expf(lrelu(as2[s0] + adn));
        float w1 = __expf(lrelu(as2[s1] + adn));
        den += w0 + w1;
        acc[0] += bflo(v0[0]) * w0 + bflo(v1[0]) * w1;
        acc[1] += bfhi(v0[0]) * w0 + bfhi(v1[0]) * w1;
        acc[2] += bflo(v0[1]) * w0 + bflo(v1[1]) * w1;
        acc[3] += bfhi(v0[1]) * w0 + bfhi(v1[1]) * w1;
    }
    if (i < end) {
        int s0 = csr_src[i]; s0 &= 0x7fffffff; if (s0 >= NN) s0 = 0;
        uint2v v0 = *(const uint2v*)(const void*)(rbase + (size_t)s0 * 128);
        float w0 = __expf(lrelu(as2[s0] + adn));
        den += w0;
        acc[0] += bflo(v0[0]) * w0;
        acc[1] += bfhi(v0[0]) * w0;
        acc[2] += bflo(v0[1]) * w0;
        acc[3] += bfhi(v0[1]) * w0;
    }

    float rden = 1.0f / fmaxf(den, 1e-30f);
    floatx4 o;
    #pragma unroll
    for (int j = 0; j < 4; ++j)
        o[j] = acc[j] * rden + loadf(b2, lane * 4 + j, f);
    *(floatx4*)(void*)(out + (size_t)n * EMB + lane * 4) = o;
}

extern "C" void kernel_launch(void* const* d_in, const int* in_sizes, int n_in,
                              void* d_out, int out_size, void* d_ws, size_t ws_size,
                              hipStream_t stream)
{
    const void* x      = d_in[0];
    const void* edge   = d_in[1];
    const void* W1     = d_in[2];
    const void* a_src1 = d_in[3];
    const void* a_dst1 = d_in[4];
    const void* b1     = d_in[5];
    const void* W2     = d_in[6];
    const void* a_src2 = d_in[7];
    const void* a_dst2 = d_in[8];
    const void* b2     = d_in[9];
    float* out = (float*)d_out;

    char* ws = (char*)d_ws;
    size_t off = 0;
    auto alloc = [&](size_t bytes) -> void* {
        void* p = ws + off;
        off += (bytes + 255) & ~(size_t)255;
        return p;
    };
    int*            counts = (int*)alloc((NN + 2) * 4);   // counts[NN]=eflag, counts[NN+1]=isf32
    int*            offs   = (int*)alloc((NN + 1) * 4);
    int*            cursor = (int*)alloc(NN * 4);
    int*            csr    = (int*)alloc((size_t)ETOT * 4);
    float*          as1    = (float*)alloc((size_t)NN * 8 * 4);
    float*          ad1    = (float*)alloc((size_t)NN * 8 * 4);
    float*          as2    = (float*)alloc((size_t)NN * 4);
    float*          ad2    = (float*)alloc((size_t)NN * 4);
    unsigned short* xb     = (unsigned short*)alloc((size_t)MPAD * IN_DIM * 2);
    unsigned short* W1t    = (unsigned short*)alloc((size_t)IN_DIM * HID1 * 2);
    unsigned short* W2t    = (unsigned short*)alloc((size_t)HID1 * EMB * 2);
    unsigned short* h1b    = (unsigned short*)alloc((size_t)MPAD * HID1 * 2);
    unsigned short* hmid   = (unsigned short*)alloc((size_t)MPAD * HID1 * 2);
    unsigned short* h2b    = (unsigned short*)alloc((size_t)MPAD * EMB * 2);
    int* eflag = counts + NN;
    int* isf32 = counts + NN + 1;

    zero_kernel<<<(NN + 2 + 255) / 256, 256, 0, stream>>>(counts, NN + 2);
    fdetect_kernel<<<1, 1024, 0, stream>>>((const unsigned*)x, isf32);
    detect_kernel<<<(E0 + 255) / 256, 256, 0, stream>>>((const int*)edge, eflag);

    count_kernel<<<(E0 + 255) / 256, 256, 0, stream>>>(edge, eflag, counts);
    scan_kernel<<<1, 1024, 0, stream>>>(counts, offs, cursor);
    scatter_kernel<<<(ETOT + 255) / 256, 256, 0, stream>>>(edge, eflag, cursor, csr);

    // bf16 conversions: x row-major; W1,W2 transposed to [N][K]
    conv_kernel<<<(NN * IN_DIM + 255) / 256, 256, 0, stream>>>(x, xb, NN * IN_DIM, isf32);
    convT_kernel<<<(IN_DIM * HID1 + 255) / 256, 256, 0, stream>>>(W1, W1t, IN_DIM, HID1, isf32);
    convT_kernel<<<(HID1 * EMB + 255) / 256, 256, 0, stream>>>(W2, W2t, HID1, EMB, isf32);

    // layer 1 GEMM (tiled MFMA): h1b (bf16) = x @ W1
    dim3 g1(MPAD / 128, HID1 / 128);
    gemm_tile<true><<<g1, 256, 0, stream>>>(xb, W1t, h1b, HID1, IN_DIM);

    alpha1_kernel<<<(NN + 3) / 4, 256, 0, stream>>>(h1b, a_src1, a_dst1, isf32, as1, ad1);
    agg1_kernel<<<(NN + 3) / 4, 256, 0, stream>>>(h1b, offs, csr, as1, ad1, b1, isf32, hmid);

    // layer 2 GEMM (tiled MFMA): h2b (bf16) = hmid @ W2
    dim3 g2(MPAD / 128, EMB / 128);
    gemm_tile<true><<<g2, 256, 0, stream>>>(hmid, W2t, h2b, EMB, HID1);

    alpha2_kernel<<<(NN + 3) / 4, 256, 0, stream>>>(h2b, a_src2, a_dst2, isf32, as2, ad2);
    agg2_kernel<<<(NN + 3) / 4, 256, 0, stream>>>(h2b, offs, csr, as2, ad2, b2, isf32, out);
}

// Round 3
// 300.041 us; speedup vs baseline: 1.1273x; 1.1273x over previous
//
#include <hip/hip_runtime.h>
#include <hip/hip_bf16.h>

typedef __attribute__((ext_vector_type(8))) short short8;
typedef __attribute__((ext_vector_type(4))) float floatx4;
typedef __attribute__((ext_vector_type(4))) unsigned short ushort4v;
typedef __attribute__((ext_vector_type(8))) unsigned short ushort8v;

#define NN 10000
#define E0 160000
#define ETOT (E0 + NN)
#define IN_DIM 512
#define HID1 1024   /* HEADS*HID = 8*128 */
#define EMB 256
#define MPAD 10112  /* 79 * 128 */
#define NX (NN * IN_DIM)
#define NW1 (IN_DIM * HID1)
#define NW2 (HID1 * EMB)

__device__ __forceinline__ float bf2f(unsigned short u) {
    unsigned v = ((unsigned)u) << 16;
    float f;
    __builtin_memcpy(&f, &v, 4);
    return f;
}
__device__ __forceinline__ unsigned short f2bf(float f) {
    unsigned u;
    __builtin_memcpy(&u, &f, 4);
    unsigned lsb = (u >> 16) & 1;
    u += 0x7fff + lsb;           // round-to-nearest-even
    return (unsigned short)(u >> 16);
}
__device__ __forceinline__ float loadf(const void* p, size_t i, int isf32) {
    if (isf32) return ((const float*)p)[i];
    return bf2f(((const unsigned short*)p)[i]);
}

// ---------------- zero fill ----------------
__global__ void zero_kernel(int* p, int n) {
    int i = blockIdx.x * 256 + threadIdx.x;
    if (i < n) p[i] = 0;
}

// ---------------- float dtype probe ----------------
__global__ __launch_bounds__(1024) void fdetect_kernel(const unsigned* xw, int* isf32) {
    __shared__ int cnt[1024];
    int t = threadIdx.x;
    int c = 0;
    #pragma unroll
    for (int j = 0; j < 4; ++j) {
        unsigned w = xw[t * 4 + j];
        int ex = (w >> 7) & 0xFF;
        if (ex >= 110 && ex <= 135) c++;
    }
    cnt[t] = c;
    __syncthreads();
    for (int off = 512; off > 0; off >>= 1) {
        if (t < off) cnt[t] += cnt[t + off];
        __syncthreads();
    }
    if (t == 0) *isf32 = (cnt[0] < 2048) ? 1 : 0;
}

// ---------------- edge dtype probe ----------------
__global__ void detect_kernel(const int* ei32, int* flag) {
    int i = blockIdx.x * 256 + threadIdx.x;
    int v = 0;
    int idx = 2 * i + 1;
    if (idx < 2 * E0) v = ei32[idx];
    unsigned long long any = __ballot(v != 0);
    if (any && (threadIdx.x & 63) == 0) atomicOr(flag, 1);
}

__device__ __forceinline__ int load_edge(const void* ei, long long idx, int m32) {
    if (m32) return ((const int*)ei)[idx];
    return (int)(((const long long*)ei)[idx]);
}

// ---------------- CSR build ----------------
__global__ void count_kernel(const void* ei, const int* flag, int* counts) {
    int e = blockIdx.x * 256 + threadIdx.x;
    if (e < E0) {
        int m32 = (*flag != 0);
        int d = load_edge(ei, (long long)E0 + e, m32);
        if (d >= 0 && d < NN) atomicAdd(&counts[d], 1);
    }
}

__global__ __launch_bounds__(1024) void scan_kernel(const int* counts, int* offsets, int* cursor) {
    __shared__ int part[1024];
    int t = threadIdx.x;
    int base = t * 10;
    int local[10];
    int s = 0;
    for (int j = 0; j < 10; ++j) {
        int idx = base + j;
        int v = (idx < NN) ? (counts[idx] + 1) : 0;  // +1 self loop
        local[j] = v; s += v;
    }
    part[t] = s;
    __syncthreads();
    for (int off = 1; off < 1024; off <<= 1) {
        int v = (t >= off) ? part[t - off] : 0;
        __syncthreads();
        part[t] += v;
        __syncthreads();
    }
    int run = (t == 0) ? 0 : part[t - 1];
    for (int j = 0; j < 10; ++j) {
        int idx = base + j;
        if (idx < NN) { offsets[idx] = run; cursor[idx] = run; run += local[j]; }
    }
    if (t == 1023) offsets[NN] = part[1023];
}

__global__ void scatter_kernel(const void* ei, const int* flag, int* cursor, int* csr_src) {
    int e = blockIdx.x * 256 + threadIdx.x;
    if (e >= ETOT) return;
    int m32 = (*flag != 0);
    int s, d;
    if (e < E0) { s = load_edge(ei, e, m32); d = load_edge(ei, (long long)E0 + e, m32); }
    else { s = d = e - E0; }
    if (s < 0) s = 0; if (s >= NN) s = NN - 1;
    if (d < 0) d = 0; if (d >= NN) d = NN - 1;
    int pos = atomicAdd(&cursor[d], 1);
    if (pos >= 0 && pos < ETOT) csr_src[pos] = s;
}

// ---------------- fused fp32->bf16 conversions (x, W1^T, W2^T in one launch) ----------------
__global__ void convall_kernel(const void* x, const void* W1, const void* W2,
                               unsigned short* xb, unsigned short* W1t, unsigned short* W2t,
                               const int* isf32)
{
    int i = blockIdx.x * 256 + threadIdx.x;
    int f = *isf32;
    if (i < NX) { xb[i] = f2bf(loadf(x, i, f)); return; }
    i -= NX;
    if (i < NW1) {
        int r = i / HID1, c = i % HID1;
        W1t[(size_t)c * IN_DIM + r] = f2bf(loadf(W1, i, f));
        return;
    }
    i -= NW1;
    if (i < NW2) {
        int r = i / EMB, c = i % EMB;
        W2t[(size_t)c * HID1 + r] = f2bf(loadf(W2, i, f));
    }
}

// ---------------- m97-style MFMA GEMM: C[Mpad,N] = A[Mpad,K] * Bt[N,K]^T ----------------
// global_load_lds width=16 staging into linear [128][32] bf16 tiles; col16 XOR-swizzle
// applied on BOTH the global source (inverse) and the ds_read (forward) — rule 21.
template<bool OUTBF16>
__global__ __launch_bounds__(256) void gemm_tile(
    const unsigned short* __restrict__ A,
    const unsigned short* __restrict__ Bt,
    void* __restrict__ Cv,
    int N, int K)
{
    __shared__ unsigned short As[128 * 32];
    __shared__ unsigned short Bs[128 * 32];
    int t = threadIdx.x;
    int wave = t >> 6;
    int lane = t & 63;
    int quad = lane >> 4;
    int l16  = lane & 15;
    int mq = wave & 1, nq = wave >> 1;
    size_t mblk = (size_t)blockIdx.x * 128;
    size_t nblk = (size_t)blockIdx.y * 128;

    floatx4 acc[4][4];
    #pragma unroll
    for (int i = 0; i < 4; ++i)
        #pragma unroll
        for (int j = 0; j < 4; ++j)
            acc[i][j] = (floatx4){0.f, 0.f, 0.f, 0.f};

    const unsigned short* Abase = A + mblk * K;
    const unsigned short* Bbase = Bt + nblk * K;

    for (int kk = 0; kk < K; kk += 32) {
        __syncthreads();   // previous iteration's fragment reads done before overwrite
        // stage: tile = 512 16B-chunks; chunk c -> row r=c>>2, col16 slot c&3.
        // stored slot (c&3) holds logical col16 (c&3)^(r&3)  (XOR involution).
        #pragma unroll
        for (int j = 0; j < 2; ++j) {
            int chunk = (wave << 7) + (j << 6) + lane;
            int r  = chunk >> 2;
            int cs = (chunk & 3) ^ (r & 3);
            const unsigned short* ga = Abase + (size_t)r * K + kk + cs * 8;
            const unsigned short* gb = Bbase + (size_t)r * K + kk + cs * 8;
            __builtin_amdgcn_global_load_lds(
                (const __attribute__((address_space(1))) void*)ga,
                (__attribute__((address_space(3))) void*)(As + (size_t)((wave << 7) + (j << 6)) * 8),
                16, 0, 0);
            __builtin_amdgcn_global_load_lds(
                (const __attribute__((address_space(1))) void*)gb,
                (__attribute__((address_space(3))) void*)(Bs + (size_t)((wave << 7) + (j << 6)) * 8),
                16, 0, 0);
        }
        __syncthreads();   // compiler inserts vmcnt(0) drain before this barrier

        short8 af[4], bf[4];
        #pragma unroll
        for (int i = 0; i < 4; ++i) {
            int ar = mq * 64 + i * 16 + l16;
            int br = nq * 64 + i * 16 + l16;
            af[i] = *(const short8*)(const void*)(As + ar * 32 + (quad ^ (ar & 3)) * 8);
            bf[i] = *(const short8*)(const void*)(Bs + br * 32 + (quad ^ (br & 3)) * 8);
        }
        #pragma unroll
        for (int i = 0; i < 4; ++i)
            #pragma unroll
            for (int j = 0; j < 4; ++j)
                acc[i][j] = __builtin_amdgcn_mfma_f32_16x16x32_bf16(af[i], bf[j], acc[i][j], 0, 0, 0);
    }

    size_t crow0 = mblk + mq * 64 + quad * 4;
    size_t ccol0 = nblk + nq * 64 + l16;
    #pragma unroll
    for (int i = 0; i < 4; ++i) {
        #pragma unroll
        for (int r = 0; r < 4; ++r) {
            size_t row = crow0 + i * 16 + r;
            size_t b = row * N + ccol0;
            #pragma unroll
            for (int j = 0; j < 4; ++j) {
                if (OUTBF16) ((unsigned short*)Cv)[b + j * 16] = f2bf(acc[i][j][r]);
                else         ((float*)Cv)[b + j * 16] = acc[i][j][r];
            }
        }
    }
}

// ---------------- alpha for layer 1 (bf16 h1): as1/ad1 [N,8] ----------------
__global__ __launch_bounds__(256) void alpha1_kernel(
    const unsigned short* __restrict__ h1,
    const void* __restrict__ a_src, const void* __restrict__ a_dst,
    const int* __restrict__ isf32,
    float* __restrict__ as1, float* __restrict__ ad1)
{
    int n = blockIdx.x, t = threadIdx.x;
    int f = *isf32;
    ushort4v hv = *(const ushort4v*)(const void*)(h1 + (size_t)n * HID1 + t * 4);
    float ps = 0.f, pd = 0.f;
    #pragma unroll
    for (int i = 0; i < 4; ++i) {
        float h = bf2f(hv[i]);
        ps += h * loadf(a_src, t * 4 + i, f);
        pd += h * loadf(a_dst, t * 4 + i, f);
    }
    __shared__ float rs[256], rdm[256];
    rs[t] = ps; rdm[t] = pd;
    __syncthreads();
    for (int off = 16; off > 0; off >>= 1) {
        if ((t & 31) < off) { rs[t] += rs[t + off]; rdm[t] += rdm[t + off]; }
        __syncthreads();
    }
    if ((t & 31) == 0) {
        int h = t >> 5;
        as1[n * 8 + h] = rs[t];
        ad1[n * 8 + h] = rdm[t];
    }
}

// ---------------- layer-1 single-pass softmax-aggregate + ELU -> hmid bf16 ----------------
// unnormalized accumulation: out = (Σ w_i h_i) / (Σ w_i); w = exp(leaky(e)), e bounded -> no max needed.
// 2 groups x 128 threads; group g handles edges beg+g, beg+g+2, ...; 16B row loads.
// 4-deep unrolled edge loop: batch independent csr / as1 / row loads to expose MLP.
__global__ __launch_bounds__(256) void agg1_kernel(
    const unsigned short* __restrict__ h1, const int* __restrict__ offsets,
    const int* __restrict__ csr_src, const float* __restrict__ as1,
    const float* __restrict__ ad1, const void* __restrict__ b1,
    const int* __restrict__ isf32,
    unsigned short* __restrict__ hmid)
{
    int n = blockIdx.x, t = threadIdx.x;
    int f = *isf32;
    int beg = offsets[n], end = offsets[n + 1];
    if (beg < 0) beg = 0; if (end > ETOT) end = ETOT;
    int g = t >> 7;          // edge group 0/1
    int u = t & 127;
    int c0 = u * 8;          // 8 cols per thread
    int hc = u >> 4;         // head = c0/128
    float ad = ad1[n * 8 + hc];

    float den = 0.f;
    float acc[8];
    #pragma unroll
    for (int j = 0; j < 8; ++j) acc[j] = 0.f;

    int i = beg + g;
    // 4 edges in flight
    for (; i + 6 < end; i += 8) {
        int s0 = csr_src[i];     s0 &= 0x7fffffff; if (s0 >= NN) s0 = 0;
        int s1 = csr_src[i + 2]; s1 &= 0x7fffffff; if (s1 >= NN) s1 = 0;
        int s2 = csr_src[i + 4]; s2 &= 0x7fffffff; if (s2 >= NN) s2 = 0;
        int s3 = csr_src[i + 6]; s3 &= 0x7fffffff; if (s3 >= NN) s3 = 0;
        ushort8v hv0 = *(const ushort8v*)(const void*)(h1 + (size_t)s0 * HID1 + c0);
        ushort8v hv1 = *(const ushort8v*)(const void*)(h1 + (size_t)s1 * HID1 + c0);
        ushort8v hv2 = *(const ushort8v*)(const void*)(h1 + (size_t)s2 * HID1 + c0);
        ushort8v hv3 = *(const ushort8v*)(const void*)(h1 + (size_t)s3 * HID1 + c0);
        float e0 = as1[s0 * 8 + hc] + ad;
        float e1 = as1[s1 * 8 + hc] + ad;
        float e2 = as1[s2 * 8 + hc] + ad;
        float e3 = as1[s3 * 8 + hc] + ad;
        e0 = e0 > 0.f ? e0 : 0.2f * e0;
        e1 = e1 > 0.f ? e1 : 0.2f * e1;
        e2 = e2 > 0.f ? e2 : 0.2f * e2;
        e3 = e3 > 0.f ? e3 : 0.2f * e3;
        float w0 = __expf(e0), w1 = __expf(e1), w2 = __expf(e2), w3 = __expf(e3);
        den += (w0 + w1) + (w2 + w3);
        #pragma unroll
        for (int j = 0; j < 8; ++j)
            acc[j] += (bf2f(hv0[j]) * w0 + bf2f(hv1[j]) * w1)
                    + (bf2f(hv2[j]) * w2 + bf2f(hv3[j]) * w3);
    }
    // 2 edges in flight
    for (; i + 2 < end; i += 4) {
        int s0 = csr_src[i];     s0 &= 0x7fffffff; if (s0 >= NN) s0 = 0;
        int s1 = csr_src[i + 2]; s1 &= 0x7fffffff; if (s1 >= NN) s1 = 0;
        ushort8v hv0 = *(const ushort8v*)(const void*)(h1 + (size_t)s0 * HID1 + c0);
        ushort8v hv1 = *(const ushort8v*)(const void*)(h1 + (size_t)s1 * HID1 + c0);
        float e0 = as1[s0 * 8 + hc] + ad;
        float e1 = as1[s1 * 8 + hc] + ad;
        e0 = e0 > 0.f ? e0 : 0.2f * e0;
        e1 = e1 > 0.f ? e1 : 0.2f * e1;
        float w0 = __expf(e0), w1 = __expf(e1);
        den += w0 + w1;
        #pragma unroll
        for (int j = 0; j < 8; ++j)
            acc[j] += bf2f(hv0[j]) * w0 + bf2f(hv1[j]) * w1;
    }
    // tail single edge
    if (i < end) {
        int s0 = csr_src[i]; s0 &= 0x7fffffff; if (s0 >= NN) s0 = 0;
        ushort8v hv0 = *(const ushort8v*)(const void*)(h1 + (size_t)s0 * HID1 + c0);
        float e0 = as1[s0 * 8 + hc] + ad;
        e0 = e0 > 0.f ? e0 : 0.2f * e0;
        float w0 = __expf(e0);
        den += w0;
        #pragma unroll
        for (int j = 0; j < 8; ++j) acc[j] += bf2f(hv0[j]) * w0;
    }

    // combine the two edge groups (inner dim padded to 9 to kill bank conflicts)
    __shared__ float accsh[128][9];
    __shared__ float densh[128];
    if (g == 1) {
        #pragma unroll
        for (int j = 0; j < 8; ++j) accsh[u][j] = acc[j];
        densh[u] = den;
    }
    __syncthreads();
    if (g == 0) {
        den += densh[u];
        float rden = 1.0f / fmaxf(den, 1e-30f);
        ushort8v outw;
        #pragma unroll
        for (int j = 0; j < 8; ++j) {
            float v = (acc[j] + accsh[u][j]) * rden + loadf(b1, c0 + j, f);
            v = v > 0.f ? v : (__expf(v) - 1.0f);   // ELU
            outw[j] = f2bf(v);
        }
        *(ushort8v*)(void*)(hmid + (size_t)n * HID1 + c0) = outw;
    }
}

// ---------------- alpha for layer 2 (bf16 h2): as2/ad2 [N] ----------------
__global__ __launch_bounds__(256) void alpha2_kernel(
    const unsigned short* __restrict__ h2,
    const void* __restrict__ a_src2, const void* __restrict__ a_dst2,
    const int* __restrict__ isf32,
    float* __restrict__ as2, float* __restrict__ ad2)
{
    int n = blockIdx.x, t = threadIdx.x;
    int f = *isf32;
    float v = bf2f(h2[(size_t)n * EMB + t]);
    float ps = v * loadf(a_src2, t, f);
    float pd = v * loadf(a_dst2, t, f);
    __shared__ float rs[256], rdm[256];
    rs[t] = ps; rdm[t] = pd;
    __syncthreads();
    for (int off = 128; off > 0; off >>= 1) {
        if (t < off) { rs[t] += rs[t + off]; rdm[t] += rdm[t + off]; }
        __syncthreads();
    }
    if (t == 0) { as2[n] = rs[0]; ad2[n] = rdm[0]; }
}

// ---------------- layer-2 single-pass softmax-aggregate -> out fp32 ----------------
// 4 groups x 64 threads; 8B bf16 row loads (64*8B = 512B row).
// 4-deep unrolled edge loop.
__global__ __launch_bounds__(256) void agg2_kernel(
    const unsigned short* __restrict__ h2, const int* __restrict__ offsets,
    const int* __restrict__ csr_src, const float* __restrict__ as2,
    const float* __restrict__ ad2, const void* __restrict__ b2,
    const int* __restrict__ isf32,
    float* __restrict__ out)
{
    int n = blockIdx.x, t = threadIdx.x;
    int f = *isf32;
    int beg = offsets[n], end = offsets[n + 1];
    if (beg < 0) beg = 0; if (end > ETOT) end = ETOT;
    int g = t >> 6;          // edge group 0..3
    int u = t & 63;
    int c0 = u * 4;          // 4 cols per thread
    float adn = ad2[n];

    float den = 0.f;
    float acc[4];
    #pragma unroll
    for (int j = 0; j < 4; ++j) acc[j] = 0.f;

    int i = beg + g;
    // 4 edges in flight (group stride is 4)
    for (; i + 12 < end; i += 16) {
        int s0 = csr_src[i];      s0 &= 0x7fffffff; if (s0 >= NN) s0 = 0;
        int s1 = csr_src[i + 4];  s1 &= 0x7fffffff; if (s1 >= NN) s1 = 0;
        int s2 = csr_src[i + 8];  s2 &= 0x7fffffff; if (s2 >= NN) s2 = 0;
        int s3 = csr_src[i + 12]; s3 &= 0x7fffffff; if (s3 >= NN) s3 = 0;
        ushort4v hv0 = *(const ushort4v*)(const void*)(h2 + (size_t)s0 * EMB + c0);
        ushort4v hv1 = *(const ushort4v*)(const void*)(h2 + (size_t)s1 * EMB + c0);
        ushort4v hv2 = *(const ushort4v*)(const void*)(h2 + (size_t)s2 * EMB + c0);
        ushort4v hv3 = *(const ushort4v*)(const void*)(h2 + (size_t)s3 * EMB + c0);
        float e0 = as2[s0] + adn;
        float e1 = as2[s1] + adn;
        float e2 = as2[s2] + adn;
        float e3 = as2[s3] + adn;
        e0 = e0 > 0.f ? e0 : 0.2f * e0;
        e1 = e1 > 0.f ? e1 : 0.2f * e1;
        e2 = e2 > 0.f ? e2 : 0.2f * e2;
        e3 = e3 > 0.f ? e3 : 0.2f * e3;
        float w0 = __expf(e0), w1 = __expf(e1), w2 = __expf(e2), w3 = __expf(e3);
        den += (w0 + w1) + (w2 + w3);
        #pragma unroll
        for (int j = 0; j < 4; ++j)
            acc[j] += (bf2f(hv0[j]) * w0 + bf2f(hv1[j]) * w1)
                    + (bf2f(hv2[j]) * w2 + bf2f(hv3[j]) * w3);
    }
    // 2 edges in flight
    for (; i + 4 < end; i += 8) {
        int s0 = csr_src[i];     s0 &= 0x7fffffff; if (s0 >= NN) s0 = 0;
        int s1 = csr_src[i + 4]; s1 &= 0x7fffffff; if (s1 >= NN) s1 = 0;
        ushort4v hv0 = *(const ushort4v*)(const void*)(h2 + (size_t)s0 * EMB + c0);
        ushort4v hv1 = *(const ushort4v*)(const void*)(h2 + (size_t)s1 * EMB + c0);
        float e0 = as2[s0] + adn;
        float e1 = as2[s1] + adn;
        e0 = e0 > 0.f ? e0 : 0.2f * e0;
        e1 = e1 > 0.f ? e1 : 0.2f * e1;
        float w0 = __expf(e0), w1 = __expf(e1);
        den += w0 + w1;
        #pragma unroll
        for (int j = 0; j < 4; ++j)
            acc[j] += bf2f(hv0[j]) * w0 + bf2f(hv1[j]) * w1;
    }
    // tail single edge
    if (i < end) {
        int s0 = csr_src[i]; s0 &= 0x7fffffff; if (s0 >= NN) s0 = 0;
        ushort4v hv0 = *(const ushort4v*)(const void*)(h2 + (size_t)s0 * EMB + c0);
        float e0 = as2[s0] + adn;
        e0 = e0 > 0.f ? e0 : 0.2f * e0;
        float w0 = __expf(e0);
        den += w0;
        #pragma unroll
        for (int j = 0; j < 4; ++j) acc[j] += bf2f(hv0[j]) * w0;
    }

    __shared__ float accsh[4][64][5];   // padded to 5: kill 8-way bank conflict
    __shared__ float densh[4][64];
    #pragma unroll
    for (int j = 0; j < 4; ++j) accsh[g][u][j] = acc[j];
    densh[g][u] = den;
    __syncthreads();
    if (g == 0) {
        float dtot = densh[0][u] + densh[1][u] + densh[2][u] + densh[3][u];
        float rden = 1.0f / fmaxf(dtot, 1e-30f);
        floatx4 o;
        #pragma unroll
        for (int j = 0; j < 4; ++j) {
            float v = (accsh[0][u][j] + accsh[1][u][j] + accsh[2][u][j] + accsh[3][u][j]) * rden;
            o[j] = v + loadf(b2, c0 + j, f);
        }
        *(floatx4*)(void*)(out + (size_t)n * EMB + c0) = o;
    }
}

extern "C" void kernel_launch(void* const* d_in, const int* in_sizes, int n_in,
                              void* d_out, int out_size, void* d_ws, size_t ws_size,
                              hipStream_t stream)
{
    const void* x      = d_in[0];
    const void* edge   = d_in[1];
    const void* W1     = d_in[2];
    const void* a_src1 = d_in[3];
    const void* a_dst1 = d_in[4];
    const void* b1     = d_in[5];
    const void* W2     = d_in[6];
    const void* a_src2 = d_in[7];
    const void* a_dst2 = d_in[8];
    const void* b2     = d_in[9];
    float* out = (float*)d_out;

    char* ws = (char*)d_ws;
    size_t off = 0;
    auto alloc = [&](size_t bytes) -> void* {
        void* p = ws + off;
        off += (bytes + 255) & ~(size_t)255;
        return p;
    };
    int*            counts = (int*)alloc((NN + 2) * 4);   // counts[NN]=eflag, counts[NN+1]=isf32
    int*            offs   = (int*)alloc((NN + 1) * 4);
    int*            cursor = (int*)alloc(NN * 4);
    int*            csr    = (int*)alloc((size_t)ETOT * 4);
    float*          as1    = (float*)alloc((size_t)NN * 8 * 4);
    float*          ad1    = (float*)alloc((size_t)NN * 8 * 4);
    float*          as2    = (float*)alloc((size_t)NN * 4);
    float*          ad2    = (float*)alloc((size_t)NN * 4);
    unsigned short* xb     = (unsigned short*)alloc((size_t)MPAD * IN_DIM * 2);
    unsigned short* W1t    = (unsigned short*)alloc((size_t)IN_DIM * HID1 * 2);
    unsigned short* W2t    = (unsigned short*)alloc((size_t)HID1 * EMB * 2);
    unsigned short* h1b    = (unsigned short*)alloc((size_t)MPAD * HID1 * 2);
    unsigned short* hmid   = (unsigned short*)alloc((size_t)MPAD * HID1 * 2);
    unsigned short* h2b    = (unsigned short*)alloc((size_t)MPAD * EMB * 2);
    int* eflag = counts + NN;
    int* isf32 = counts + NN + 1;

    zero_kernel<<<(NN + 2 + 255) / 256, 256, 0, stream>>>(counts, NN + 2);
    fdetect_kernel<<<1, 1024, 0, stream>>>((const unsigned*)x, isf32);
    detect_kernel<<<(E0 + 255) / 256, 256, 0, stream>>>((const int*)edge, eflag);

    count_kernel<<<(E0 + 255) / 256, 256, 0, stream>>>(edge, eflag, counts);
    scan_kernel<<<1, 1024, 0, stream>>>(counts, offs, cursor);
    scatter_kernel<<<(ETOT + 255) / 256, 256, 0, stream>>>(edge, eflag, cursor, csr);

    // fused bf16 conversions: x row-major; W1,W2 transposed to [N][K]
    convall_kernel<<<(NX + NW1 + NW2 + 255) / 256, 256, 0, stream>>>(
        x, W1, W2, xb, W1t, W2t, isf32);

    // layer 1 GEMM (m97-style MFMA): h1b (bf16) = x @ W1
    dim3 g1(MPAD / 128, HID1 / 128);
    gemm_tile<true><<<g1, 256, 0, stream>>>(xb, W1t, h1b, HID1, IN_DIM);

    alpha1_kernel<<<NN, 256, 0, stream>>>(h1b, a_src1, a_dst1, isf32, as1, ad1);
    agg1_kernel<<<NN, 256, 0, stream>>>(h1b, offs, csr, as1, ad1, b1, isf32, hmid);

    // layer 2 GEMM (m97-style MFMA): h2b (bf16) = hmid @ W2
    dim3 g2(MPAD / 128, EMB / 128);
    gemm_tile<true><<<g2, 256, 0, stream>>>(hmid, W2t, h2b, EMB, HID1);

    alpha2_kernel<<<NN, 256, 0, stream>>>(h2b, a_src2, a_dst2, isf32, as2, ad2);
    agg2_kernel<<<NN, 256, 0, stream>>>(h2b, offs, csr, as2, ad2, b2, isf32, out);
}